// Round 10
// baseline (225.755 us; speedup 1.0000x reference)
//
#include <hip/hip_runtime.h>

#define N_NODES 20000
#define N_EDGES 160000
#define N_PAIRS 50000
#define DMAX 48
// F_IN = CHANNELS = 32, EDGE_DIM = 8

__device__ __forceinline__ float4 f4fma(float s, float4 w, float4 a) {
    a.x += s * w.x; a.y += s * w.y; a.z += s * w.z; a.w += s * w.w;
    return a;
}

__global__ void zero_cnt(int* __restrict__ c) {
    int t = blockIdx.x * blockDim.x + threadIdx.x;
    if (t < N_NODES) c[t] = 0;
}

// adjacency by target: slot -> src node + a copy of the edge's 8 attrs
// (sequential reads at gather time; only X[src] stays random)
__global__ __launch_bounds__(256) void fill_adj(const int* __restrict__ ei,
                                                const float* __restrict__ E,
                                                int* __restrict__ cnt,
                                                int* __restrict__ adjsrc,
                                                float4* __restrict__ adjE4) {
    int e = blockIdx.x * blockDim.x + threadIdx.x;
    if (e >= N_EDGES) return;
    int2 st = ((const int2*)ei)[e];  // x = src, y = tgt
    int slot = atomicAdd(&cnt[st.y], 1);
    if (slot < DMAX) {
        int idx = st.y * DMAX + slot;
        adjsrc[idx] = st.x;
        const float4* s = (const float4*)(E + (size_t)e * 8);
        adjE4[idx * 2 + 0] = s[0];
        adjE4[idx * 2 + 1] = s[1];
    }
}

// One wave per node. Phase 1: both wave halves gather G (even/odd edges),
// combine via shfl_xor(32), park G (328 floats) in LDS.
//   G[d*32+i] = sum_e e_d * X[src][i]  (d<8) | G[256+i] = sum_e X[src][i]
//   G[288+i]  = X[n][i]
// Phase 2: 320x32 GEMM vs W' = [knw|knb|root] verbatim (L1-hot), thread =
// (j = out chunk of 4, s = k-slice); k4 = s+8m -> banks 4s, conflict-free.
// mode 0: H[n][o] = relu(out + bias[o])
// mode 1: util[n] = db + sum_o relu(out + bias[o]) * dw[o]
__global__ __launch_bounds__(256) void layer_kernel(const float* __restrict__ X,
                                                    const int* __restrict__ cnt,
                                                    const int* __restrict__ adjsrc,
                                                    const float4* __restrict__ adjE4,
                                                    const float* __restrict__ knw,
                                                    const float* __restrict__ knb,
                                                    const float* __restrict__ root,
                                                    const float* __restrict__ bias,
                                                    const float* __restrict__ dw,
                                                    const float* __restrict__ db,
                                                    float* __restrict__ H,
                                                    float* __restrict__ util,
                                                    int mode) {
    __shared__ float Gs[4 * 328];
    int t = threadIdx.x;
    int wv = t >> 6;                    // wave = local node
    int n = blockIdx.x * 4 + wv;
    int lane = t & 63;
    int i = lane & 31;
    int half = lane >> 5;

    // ---- phase 1: gather ----
    float g0 = 0.f, g1 = 0.f, g2 = 0.f, g3 = 0.f;
    float g4 = 0.f, g5 = 0.f, g6 = 0.f, g7 = 0.f, g8 = 0.f;
    {
        int deg = min(cnt[n], DMAX);
        int base = n * DMAX;
        for (int k = half; k < deg; k += 2) {
            int src = adjsrc[base + k];
            float4 ea = adjE4[(base + k) * 2 + 0];
            float4 eb = adjE4[(base + k) * 2 + 1];
            float xv = X[src * 32 + i];  // 128B line, L2-resident (2.56MB)
            g0 += ea.x * xv; g1 += ea.y * xv; g2 += ea.z * xv; g3 += ea.w * xv;
            g4 += eb.x * xv; g5 += eb.y * xv; g6 += eb.z * xv; g7 += eb.w * xv;
            g8 += xv;
        }
    }
    g0 += __shfl_xor(g0, 32); g1 += __shfl_xor(g1, 32);
    g2 += __shfl_xor(g2, 32); g3 += __shfl_xor(g3, 32);
    g4 += __shfl_xor(g4, 32); g5 += __shfl_xor(g5, 32);
    g6 += __shfl_xor(g6, 32); g7 += __shfl_xor(g7, 32);
    g8 += __shfl_xor(g8, 32);
    if (half == 0) {
        float* gr = &Gs[wv * 328];
        gr[0 * 32 + i] = g0; gr[1 * 32 + i] = g1;
        gr[2 * 32 + i] = g2; gr[3 * 32 + i] = g3;
        gr[4 * 32 + i] = g4; gr[5 * 32 + i] = g5;
        gr[6 * 32 + i] = g6; gr[7 * 32 + i] = g7;
        gr[256 + i] = g8;
        gr[288 + i] = X[n * 32 + i];
    }
    __syncthreads();

    // ---- phase 2: GEMM epilogue ----
    int j = (lane >> 3) & 7;   // output chunk 4j..4j+3
    int s = lane & 7;          // k-slice
    const float* grow = &Gs[wv * 328];
    float4 a = make_float4(0.f, 0.f, 0.f, 0.f);

    const float4* Wk = (const float4*)knw;
#pragma unroll
    for (int m = 0; m < 8; ++m) {
        int k4 = s + 8 * m;
        float4 gg = *(const float4*)&grow[k4 * 4];
        float4 w0 = Wk[(k4 * 4 + 0) * 8 + j];
        float4 w1 = Wk[(k4 * 4 + 1) * 8 + j];
        float4 w2 = Wk[(k4 * 4 + 2) * 8 + j];
        float4 w3 = Wk[(k4 * 4 + 3) * 8 + j];
        a = f4fma(gg.x, w0, a); a = f4fma(gg.y, w1, a);
        a = f4fma(gg.z, w2, a); a = f4fma(gg.w, w3, a);
    }
    {
        const float4* Kb = (const float4*)knb;       // k4 = 64+s
        float4 gg = *(const float4*)&grow[(64 + s) * 4];
        float4 w0 = Kb[(s * 4 + 0) * 8 + j];
        float4 w1 = Kb[(s * 4 + 1) * 8 + j];
        float4 w2 = Kb[(s * 4 + 2) * 8 + j];
        float4 w3 = Kb[(s * 4 + 3) * 8 + j];
        a = f4fma(gg.x, w0, a); a = f4fma(gg.y, w1, a);
        a = f4fma(gg.z, w2, a); a = f4fma(gg.w, w3, a);
    }
    {
        const float4* Rt = (const float4*)root;      // k4 = 72+s
        float4 gg = *(const float4*)&grow[(72 + s) * 4];
        float4 w0 = Rt[(s * 4 + 0) * 8 + j];
        float4 w1 = Rt[(s * 4 + 1) * 8 + j];
        float4 w2 = Rt[(s * 4 + 2) * 8 + j];
        float4 w3 = Rt[(s * 4 + 3) * 8 + j];
        a = f4fma(gg.x, w0, a); a = f4fma(gg.y, w1, a);
        a = f4fma(gg.z, w2, a); a = f4fma(gg.w, w3, a);
    }

    // butterfly-reduce over s (lane bits 0..2): all lanes end with node total
    a.x += __shfl_xor(a.x, 1); a.y += __shfl_xor(a.y, 1);
    a.z += __shfl_xor(a.z, 1); a.w += __shfl_xor(a.w, 1);
    a.x += __shfl_xor(a.x, 2); a.y += __shfl_xor(a.y, 2);
    a.z += __shfl_xor(a.z, 2); a.w += __shfl_xor(a.w, 2);
    a.x += __shfl_xor(a.x, 4); a.y += __shfl_xor(a.y, 4);
    a.z += __shfl_xor(a.z, 4); a.w += __shfl_xor(a.w, 4);

    float4 b = ((const float4*)bias)[j];
    if (mode == 0) {
        if (s == 0) {
            float4 v;
            v.x = fmaxf(a.x + b.x, 0.f); v.y = fmaxf(a.y + b.y, 0.f);
            v.z = fmaxf(a.z + b.z, 0.f); v.w = fmaxf(a.w + b.w, 0.f);
            ((float4*)H)[n * 8 + j] = v;
        }
    } else {
        float4 dv = ((const float4*)dw)[j];
        float p = fmaxf(a.x + b.x, 0.f) * dv.x + fmaxf(a.y + b.y, 0.f) * dv.y
                + fmaxf(a.z + b.z, 0.f) * dv.z + fmaxf(a.w + b.w, 0.f) * dv.w;
        p += __shfl_xor(p, 8);
        p += __shfl_xor(p, 16);
        p += __shfl_xor(p, 32);
        if (lane == 0) util[n] = p + db[0];
    }
}

// out[p] = util[idx_b[p]] - util[idx_a[p]]
__global__ void pair_kernel(const float* __restrict__ util, const int* __restrict__ ia,
                            const int* __restrict__ ib, float* __restrict__ out) {
    int p = blockIdx.x * blockDim.x + threadIdx.x;
    if (p >= N_PAIRS) return;
    out[p] = util[ib[p]] - util[ia[p]];
}

extern "C" void kernel_launch(void* const* d_in, const int* in_sizes, int n_in,
                              void* d_out, int out_size, void* d_ws, size_t ws_size,
                              hipStream_t stream) {
    const float* x     = (const float*)d_in[0];
    const float* e     = (const float*)d_in[1];
    const float* knw1  = (const float*)d_in[2];
    const float* knb1  = (const float*)d_in[3];
    const float* root1 = (const float*)d_in[4];
    const float* bias1 = (const float*)d_in[5];
    const float* knw2  = (const float*)d_in[6];
    const float* knb2  = (const float*)d_in[7];
    const float* root2 = (const float*)d_in[8];
    const float* bias2 = (const float*)d_in[9];
    const float* dw    = (const float*)d_in[10];
    const float* db    = (const float*)d_in[11];
    const int*   ei    = (const int*)d_in[12];
    const int*   ia    = (const int*)d_in[13];
    const int*   ib    = (const int*)d_in[14];
    float* out = (float*)d_out;

    float* ws = (float*)d_ws;
    float* H      = ws;                       // 640,000 floats
    float* util   = ws + 640000;              // 20,000
    int*   cnt    = (int*)(ws + 660000);      // 20,000
    int*   adjsrc = (int*)(ws + 680000);      // 960,000
    float* adjE   = ws + 1640000;             // 7,680,000 (960000 slots * 32B)

    // ---- adjacency ----
    zero_cnt<<<(N_NODES + 255) / 256, 256, 0, stream>>>(cnt);
    fill_adj<<<(N_EDGES + 255) / 256, 256, 0, stream>>>(ei, e, cnt, adjsrc,
                                                        (float4*)adjE);

    // ---- layer 1 ----
    layer_kernel<<<N_NODES / 4, 256, 0, stream>>>(x, cnt, adjsrc, (const float4*)adjE,
                                                  knw1, knb1, root1, bias1, dw, db,
                                                  H, util, 0);
    // ---- layer 2 (+ readout) ----
    layer_kernel<<<N_NODES / 4, 256, 0, stream>>>(H, cnt, adjsrc, (const float4*)adjE,
                                                  knw2, knb2, root2, bias2, dw, db,
                                                  H, util, 1);

    // ---- pairs ----
    pair_kernel<<<(N_PAIRS + 255) / 256, 256, 0, stream>>>(util, ia, ib, out);
}

// Round 11
// 113.007 us; speedup vs baseline: 1.9977x; 1.9977x over previous
//
#include <hip/hip_runtime.h>

#define N_NODES 20000
#define N_EDGES 160000
#define N_PAIRS 50000
#define DMAX 48
#define MB 64          // nodes per epi block
// F_IN = CHANNELS = 32, EDGE_DIM = 8; G row = 288 floats (knw 256 + knb 32)

__device__ __forceinline__ float4 f4fma(float s, float4 w, float4 a) {
    a.x += s * w.x; a.y += s * w.y; a.z += s * w.z; a.w += s * w.w;
    return a;
}

__global__ void zero_cnt(int* __restrict__ c) {
    int t = blockIdx.x * blockDim.x + threadIdx.x;
    if (t < N_NODES) c[t] = 0;
}

// adjacency by target: slot -> src node + copy of the edge's 8 attrs
__global__ __launch_bounds__(256) void fill_adj(const int* __restrict__ ei,
                                                const float* __restrict__ E,
                                                int* __restrict__ cnt,
                                                int* __restrict__ adjsrc,
                                                float4* __restrict__ adjE4) {
    int e = blockIdx.x * blockDim.x + threadIdx.x;
    if (e >= N_EDGES) return;
    int2 st = ((const int2*)ei)[e];  // x = src, y = tgt
    int slot = atomicAdd(&cnt[st.y], 1);
    if (slot < DMAX) {
        int idx = st.y * DMAX + slot;
        adjsrc[idx] = st.x;
        const float4* s = (const float4*)(E + (size_t)e * 8);
        adjE4[idx * 2 + 0] = s[0];
        adjE4[idx * 2 + 1] = s[1];
    }
}

// G gather: 32-lane group per node (8 nodes / 256-thr block), lane = channel i.
//   G[n][d*32+i] = sum_{e->n} e_d * X[src][i]   (d=0..7)
//   G[n][256+i]  = sum_{e->n} X[src][i]
// All adj reads sequential; only X[src] random (2.56MB, L2-resident).
__global__ __launch_bounds__(256) void edge_gather(const float* __restrict__ X,
                                                   const int* __restrict__ cnt,
                                                   const int* __restrict__ adjsrc,
                                                   const float4* __restrict__ adjE4,
                                                   float* __restrict__ G) {
    int t = blockIdx.x * blockDim.x + threadIdx.x;
    int n = t >> 5;
    if (n >= N_NODES) return;
    int i = t & 31;
    int deg = min(cnt[n], DMAX);
    float g0 = 0.f, g1 = 0.f, g2 = 0.f, g3 = 0.f;
    float g4 = 0.f, g5 = 0.f, g6 = 0.f, g7 = 0.f, g8 = 0.f;
    int base = n * DMAX;
    for (int k = 0; k < deg; ++k) {
        int src = adjsrc[base + k];
        float4 ea = adjE4[(base + k) * 2 + 0];
        float4 eb = adjE4[(base + k) * 2 + 1];
        float xv = X[src * 32 + i];
        g0 += ea.x * xv; g1 += ea.y * xv; g2 += ea.z * xv; g3 += ea.w * xv;
        g4 += eb.x * xv; g5 += eb.y * xv; g6 += eb.z * xv; g7 += eb.w * xv;
        g8 += xv;
    }
    float* gr = G + (size_t)n * 288;
    gr[0 * 32 + i] = g0; gr[1 * 32 + i] = g1;
    gr[2 * 32 + i] = g2; gr[3 * 32 + i] = g3;
    gr[4 * 32 + i] = g4; gr[5 * 32 + i] = g5;
    gr[6 * 32 + i] = g6; gr[7 * 32 + i] = g7;
    gr[256 + i] = g8;
}

// Epilogue GEMM: out[n][o] = sum_k Gext[n][k] * W'[k][o], K=320, N=32.
//   W' = [knw | knb | root] verbatim; Gext rows 0..287 = G, rows 288..319 = X.
// Block: 64 nodes, 256 threads; thread (mg = t>>3, jg = t&7) -> nodes
// {2mg, 2mg+1} x outputs {4jg..4jg+3}. W' staged once in LDS (40KB); G/X
// streamed in 9 transposed k-chunks (<=36 x 64, stride 65 -> conflict-light).
// mode 0: H[n][o] = relu(out + bias[o]);  mode 1: util[n] = db + relu(.)@dw
__global__ __launch_bounds__(256) void epi_gemm(const float4* __restrict__ G4,
                                                const float4* __restrict__ X4,
                                                const float4* __restrict__ knw4,
                                                const float4* __restrict__ knb4,
                                                const float4* __restrict__ root4,
                                                const float* __restrict__ bias,
                                                const float* __restrict__ dw,
                                                const float* __restrict__ db,
                                                float* __restrict__ H,
                                                float* __restrict__ util,
                                                int mode) {
    __shared__ float Ws[320 * 32];   // 40960 B
    __shared__ float Gs[36 * 65];    //  9360 B
    int t = threadIdx.x;
    int nb = blockIdx.x * MB;

    // stage W' = [knw | knb | root] verbatim
    {
        float4* d = (float4*)Ws;
#pragma unroll
        for (int c = 0; c < 10; ++c) {
            int idx = c * 256 + t;
            float4 v;
            if (idx < 2048) v = knw4[idx];
            else if (idx < 2304) v = knb4[idx - 2048];
            else v = root4[idx - 2304];
            d[idx] = v;
        }
    }

    int mg = t >> 3, jg = t & 7;
    float4 a0 = make_float4(0.f, 0.f, 0.f, 0.f);
    float4 a1 = a0;
    int n0 = nb + 2 * mg, n1 = n0 + 1;

    for (int ch = 0; ch < 9; ++ch) {
        __syncthreads();  // Ws ready (ch 0) / previous chunk consumed
        if (ch < 8) {
            for (int idx = t; idx < MB * 9; idx += 256) {
                int n = idx / 9, k4 = idx % 9;
                float4 v = make_float4(0.f, 0.f, 0.f, 0.f);
                if (nb + n < N_NODES) v = G4[(size_t)(nb + n) * 72 + ch * 9 + k4];
                int r = k4 * 4;
                Gs[(r + 0) * 65 + n] = v.x; Gs[(r + 1) * 65 + n] = v.y;
                Gs[(r + 2) * 65 + n] = v.z; Gs[(r + 3) * 65 + n] = v.w;
            }
        } else {
            for (int idx = t; idx < MB * 8; idx += 256) {
                int n = idx / 8, k4 = idx % 8;
                float4 v = make_float4(0.f, 0.f, 0.f, 0.f);
                if (nb + n < N_NODES) v = X4[(size_t)(nb + n) * 8 + k4];
                int r = k4 * 4;
                Gs[(r + 0) * 65 + n] = v.x; Gs[(r + 1) * 65 + n] = v.y;
                Gs[(r + 2) * 65 + n] = v.z; Gs[(r + 3) * 65 + n] = v.w;
            }
        }
        __syncthreads();
        int kbase = (ch < 8) ? ch * 36 : 288;
        int klen = (ch < 8) ? 36 : 32;
        for (int kk = 0; kk < klen; ++kk) {
            float4 w = *(const float4*)&Ws[(kbase + kk) * 32 + jg * 4];
            float2 g = *(const float2*)&Gs[kk * 65 + 2 * mg];
            a0 = f4fma(g.x, w, a0);
            a1 = f4fma(g.y, w, a1);
        }
    }

    float4 b = ((const float4*)bias)[jg];
    if (mode == 0) {
        float4 v;
        if (n0 < N_NODES) {
            v.x = fmaxf(a0.x + b.x, 0.f); v.y = fmaxf(a0.y + b.y, 0.f);
            v.z = fmaxf(a0.z + b.z, 0.f); v.w = fmaxf(a0.w + b.w, 0.f);
            ((float4*)H)[n0 * 8 + jg] = v;
        }
        if (n1 < N_NODES) {
            v.x = fmaxf(a1.x + b.x, 0.f); v.y = fmaxf(a1.y + b.y, 0.f);
            v.z = fmaxf(a1.z + b.z, 0.f); v.w = fmaxf(a1.w + b.w, 0.f);
            ((float4*)H)[n1 * 8 + jg] = v;
        }
    } else {
        float4 dv = ((const float4*)dw)[jg];
        float p0 = fmaxf(a0.x + b.x, 0.f) * dv.x + fmaxf(a0.y + b.y, 0.f) * dv.y
                 + fmaxf(a0.z + b.z, 0.f) * dv.z + fmaxf(a0.w + b.w, 0.f) * dv.w;
        float p1 = fmaxf(a1.x + b.x, 0.f) * dv.x + fmaxf(a1.y + b.y, 0.f) * dv.y
                 + fmaxf(a1.z + b.z, 0.f) * dv.z + fmaxf(a1.w + b.w, 0.f) * dv.w;
        p0 += __shfl_xor(p0, 1); p1 += __shfl_xor(p1, 1);
        p0 += __shfl_xor(p0, 2); p1 += __shfl_xor(p1, 2);
        p0 += __shfl_xor(p0, 4); p1 += __shfl_xor(p1, 4);
        if (jg == 0) {
            float dbv = db[0];
            if (n0 < N_NODES) util[n0] = p0 + dbv;
            if (n1 < N_NODES) util[n1] = p1 + dbv;
        }
    }
}

// out[p] = util[idx_b[p]] - util[idx_a[p]]
__global__ void pair_kernel(const float* __restrict__ util, const int* __restrict__ ia,
                            const int* __restrict__ ib, float* __restrict__ out) {
    int p = blockIdx.x * blockDim.x + threadIdx.x;
    if (p >= N_PAIRS) return;
    out[p] = util[ib[p]] - util[ia[p]];
}

extern "C" void kernel_launch(void* const* d_in, const int* in_sizes, int n_in,
                              void* d_out, int out_size, void* d_ws, size_t ws_size,
                              hipStream_t stream) {
    const float* x     = (const float*)d_in[0];
    const float* e     = (const float*)d_in[1];
    const float* knw1  = (const float*)d_in[2];
    const float* knb1  = (const float*)d_in[3];
    const float* root1 = (const float*)d_in[4];
    const float* bias1 = (const float*)d_in[5];
    const float* knw2  = (const float*)d_in[6];
    const float* knb2  = (const float*)d_in[7];
    const float* root2 = (const float*)d_in[8];
    const float* bias2 = (const float*)d_in[9];
    const float* dw    = (const float*)d_in[10];
    const float* db    = (const float*)d_in[11];
    const int*   ei    = (const int*)d_in[12];
    const int*   ia    = (const int*)d_in[13];
    const int*   ib    = (const int*)d_in[14];
    float* out = (float*)d_out;

    float* ws = (float*)d_ws;
    float* G      = ws;                       // 20000*288 = 5,760,000 floats
    float* H      = ws + 5760000;             // 640,000
    float* util   = ws + 6400000;             // 20,000
    int*   cnt    = (int*)(ws + 6420000);     // 20,000
    int*   adjsrc = (int*)(ws + 6440000);     // 960,000
    float* adjE   = ws + 7400000;             // 7,680,000 (960000 slots * 32B)

    int nblk_epi = (N_NODES + MB - 1) / MB;   // 313

    // ---- adjacency ----
    zero_cnt<<<(N_NODES + 255) / 256, 256, 0, stream>>>(cnt);
    fill_adj<<<(N_EDGES + 255) / 256, 256, 0, stream>>>(ei, e, cnt, adjsrc,
                                                        (float4*)adjE);

    // ---- layer 1 ----
    edge_gather<<<(N_NODES * 32) / 256, 256, 0, stream>>>(x, cnt, adjsrc,
                                                          (const float4*)adjE, G);
    epi_gemm<<<nblk_epi, 256, 0, stream>>>((const float4*)G, (const float4*)x,
                                           (const float4*)knw1, (const float4*)knb1,
                                           (const float4*)root1, bias1, dw, db,
                                           H, util, 0);
    // ---- layer 2 (+ readout) ----
    edge_gather<<<(N_NODES * 32) / 256, 256, 0, stream>>>(H, cnt, adjsrc,
                                                          (const float4*)adjE, G);
    epi_gemm<<<nblk_epi, 256, 0, stream>>>((const float4*)G, (const float4*)H,
                                           (const float4*)knw2, (const float4*)knb2,
                                           (const float4*)root2, bias2, dw, db,
                                           H, util, 1);

    // ---- pairs ----
    pair_kernel<<<(N_PAIRS + 255) / 256, 256, 0, stream>>>(util, ia, ib, out);
}